// Round 8
// baseline (84.882 us; speedup 1.0000x reference)
//
#include <hip/hip_runtime.h>
#include <hip/hip_bf16.h>

typedef float    f32x4 __attribute__((ext_vector_type(4)));
typedef _Float16 f16x8 __attribute__((ext_vector_type(8)));
typedef unsigned int   u32x4 __attribute__((ext_vector_type(4)));
typedef unsigned short u16x4 __attribute__((ext_vector_type(4)));

#define NB 32
#define NA 64
#define NF 128
#define NC 128

// ---------------------------------------------------------------------------
// MEASUREMENT ROUND: identical to R7 except the main kernel is launched 4x.
// main_est = (T_R8 - T_R7) / 3 splits prep+overhead vs main time.
// ---------------------------------------------------------------------------
__global__ __launch_bounds__(512) void prep_kernel(
    const float* __restrict__ x, const float* __restrict__ W0,
    const float* __restrict__ b0, const float* __restrict__ W1,
    _Float16* __restrict__ u, _Float16* __restrict__ v,
    _Float16* __restrict__ w1f)
{
    int blk = blockIdx.x;
    int tid = threadIdx.x;
    if (blk < 256) {
        __shared__ __align__(16) float xs[8 * 128];
        int b = blk >> 3;
        int g = blk & 7;
        if (tid < 256)
            ((f32x4*)xs)[tid] =
                ((const f32x4*)(x + (size_t)(b * NA + g * 8) * NF))[tid];
        __syncthreads();
        int c = tid & 127;
        int h = (tid >> 7) & 1;   // 0 -> u, 1 -> v
        int s = tid >> 8;         // atom sub-group: 4 atoms
        const float* wp = W0 + (size_t)h * 128 * NC + c;
        const float* xp = xs + s * 4 * 128;
        float a0 = 0.f, a1 = 0.f, a2 = 0.f, a3 = 0.f;
        #pragma unroll 8
        for (int f = 0; f < 128; ++f) {
            float w = wp[(size_t)f * NC];
            a0 = fmaf(xp[f],       w, a0);
            a1 = fmaf(xp[128 + f], w, a1);
            a2 = fmaf(xp[256 + f], w, a2);
            a3 = fmaf(xp[384 + f], w, a3);
        }
        int row = b * NA + g * 8 + s * 4;
        if (h == 0) {
            u[(size_t)(row + 0) * NC + c] = (_Float16)a0;
            u[(size_t)(row + 1) * NC + c] = (_Float16)a1;
            u[(size_t)(row + 2) * NC + c] = (_Float16)a2;
            u[(size_t)(row + 3) * NC + c] = (_Float16)a3;
        } else {
            float bb = b0[c];
            v[(size_t)(row + 0) * NC + c] = (_Float16)(a0 + bb);
            v[(size_t)(row + 1) * NC + c] = (_Float16)(a1 + bb);
            v[(size_t)(row + 2) * NC + c] = (_Float16)(a2 + bb);
            v[(size_t)(row + 3) * NC + c] = (_Float16)(a3 + bb);
        }
    } else {
        int idx  = ((blk - 256) * 512 + tid) * 4;  // 0..16383, step 4
        int e0   = idx & 7;                        // 0 or 4
        int fl   = idx >> 3;
        int lane = fl & 63;
        int frag = fl >> 6;                        // 0..31
        int kk = frag >> 3, nf = frag & 7;
        int k = kk * 32 + (lane >> 4) * 8 + e0;
        int n = nf * 16 + (lane & 15);
        u16x4 o;
        #pragma unroll
        for (int e = 0; e < 4; ++e) {
            _Float16 w = (_Float16)W1[(size_t)(k + e) * NC + n];
            o[e] = __builtin_bit_cast(unsigned short, w);
        }
        *(u16x4*)(w1f + idx) = o;
    }
}

__global__ __launch_bounds__(256, 3) void pair_mlp_kernel(
    const float* __restrict__ b1g, const _Float16* __restrict__ u,
    const _Float16* __restrict__ v, const _Float16* __restrict__ w1f,
    float* __restrict__ out)
{
    __shared__ __align__(16) _Float16 u_s[16 * 128];   // 4 KB
    __shared__ __align__(16) _Float16 v_s[16 * 128];   // 4 KB
    __shared__ __align__(16) _Float16 w_s[32 * 64 * 8]; // 32 KB, frag-major

    int blk = blockIdx.x;
    int b = blk / 36;
    int t = blk % 36;
    int I = 0;
    while (t >= 8 - I) { t -= 8 - I; ++I; }
    int J = I + t;

    int tid = threadIdx.x;

    {
        int row = tid >> 4;            // 0..15
        int c   = tid & 15;            // 16B chunk within 256B row
        int ga  = b * NA + ((row < 8) ? (I * 8 + row) : (J * 8 + (row & 7)));
        ((u32x4*)u_s)[tid] = ((const u32x4*)(u + (size_t)ga * NC))[c];
        ((u32x4*)v_s)[tid] = ((const u32x4*)(v + (size_t)ga * NC))[c];
    }
    #pragma unroll
    for (int p = 0; p < 8; ++p)
        ((u32x4*)w_s)[p * 256 + tid] = ((const u32x4*)w1f)[p * 256 + tid];
    __syncthreads();

    int wave = tid >> 6;
    int lane = tid & 63;
    int llo  = lane & 15;
    int lhi  = lane >> 4;
    int r    = wave * 16 + llo;
    int il   = r >> 3;
    int jl   = r & 7;

    f32x4 acc0[8], acc1[8];
    f32x4 z = {0.f, 0.f, 0.f, 0.f};
    #pragma unroll
    for (int nf = 0; nf < 8; ++nf) { acc0[nf] = z; acc1[nf] = z; }

    const f16x8* uI = (const f16x8*)(u_s + il * 128);
    const f16x8* vI = (const f16x8*)(v_s + il * 128);
    const f16x8* uJ = (const f16x8*)(u_s + (8 + jl) * 128);
    const f16x8* vJ = (const f16x8*)(v_s + (8 + jl) * 128);
    const f16x8* wf = (const f16x8*)w_s;

    #pragma unroll
    for (int kk = 0; kk < 4; ++kk) {
        int kc = kk * 4 + lhi;

        f16x8 uIv = uI[kc];
        f16x8 vIv = vI[kc];
        f16x8 uJv = uJ[kc];
        f16x8 vJv = vJ[kc];

        f16x8 s0 = uIv + vJv;
        f16x8 s1 = uJv + vIv;
        f16x8 h0, h1;
        #pragma unroll
        for (int e = 0; e < 8; ++e) {
            h0[e] = s0[e] < (_Float16)0 ? (_Float16)0 : s0[e];
            h1[e] = s1[e] < (_Float16)0 ? (_Float16)0 : s1[e];
        }

        #pragma unroll
        for (int nf = 0; nf < 8; ++nf) {
            f16x8 w = wf[(kk * 8 + nf) * 64 + lane];
            acc0[nf] = __builtin_amdgcn_mfma_f32_16x16x32_f16(w, h0, acc0[nf], 0, 0, 0);
            acc1[nf] = __builtin_amdgcn_mfma_f32_16x16x32_f16(w, h1, acc1[nf], 0, 0, 0);
        }
    }

    int Ig = I * 8 + il;
    int Jg = J * 8 + jl;
    float* p1 = out + ((size_t)b * 4096 + Ig * 64 + Jg) * 128 + lhi * 4;
    float* p2 = out + ((size_t)b * 4096 + Jg * 64 + Ig) * 128 + lhi * 4;
    bool mirror = (I != J);
    #pragma unroll
    for (int nf = 0; nf < 8; ++nf) {
        f32x4 bias = *(const f32x4*)(b1g + nf * 16 + lhi * 4);
        f32x4 val;
        #pragma unroll
        for (int e = 0; e < 4; ++e)
            val[e] = fmaxf(acc0[nf][e] + bias[e], 0.f) +
                     fmaxf(acc1[nf][e] + bias[e], 0.f);
        *(f32x4*)(p1 + nf * 16) = val;
        if (mirror)
            *(f32x4*)(p2 + nf * 16) = val;
    }
}

extern "C" void kernel_launch(void* const* d_in, const int* in_sizes, int n_in,
                              void* d_out, int out_size, void* d_ws, size_t ws_size,
                              hipStream_t stream)
{
    (void)in_sizes; (void)n_in; (void)out_size; (void)ws_size;
    const float* x  = (const float*)d_in[0];
    const float* W0 = (const float*)d_in[1];
    const float* b0 = (const float*)d_in[2];
    const float* W1 = (const float*)d_in[3];
    const float* b1 = (const float*)d_in[4];
    float* out = (float*)d_out;

    _Float16* u   = (_Float16*)d_ws;                       // 0.5 MB
    _Float16* v   = u + (size_t)NB * NA * NC;              // 0.5 MB
    _Float16* w1f = v + (size_t)NB * NA * NC;              // 32 KB

    prep_kernel<<<264, 512, 0, stream>>>(x, W0, b0, W1, u, v, w1f);
    // 4x identical, idempotent main launches: main ~= (T_R8 - T_R7) / 3
    pair_mlp_kernel<<<32 * 36, 256, 0, stream>>>(b1, u, v, w1f, out);
    pair_mlp_kernel<<<32 * 36, 256, 0, stream>>>(b1, u, v, w1f, out);
    pair_mlp_kernel<<<32 * 36, 256, 0, stream>>>(b1, u, v, w1f, out);
    pair_mlp_kernel<<<32 * 36, 256, 0, stream>>>(b1, u, v, w1f, out);
}

// Round 9
// 29.899 us; speedup vs baseline: 2.8390x; 2.8390x over previous
//
#include <hip/hip_runtime.h>
#include <hip/hip_bf16.h>

typedef float    f32x4 __attribute__((ext_vector_type(4)));
typedef _Float16 f16x4 __attribute__((ext_vector_type(4)));
typedef _Float16 f16x8 __attribute__((ext_vector_type(8)));
typedef unsigned int   u32x4 __attribute__((ext_vector_type(4)));

#define NB 32
#define NA 64
#define NF 128
#define NC 128

// ---------------------------------------------------------------------------
// prep (MFMA-based):
//  blocks 0..255 : task (b, g, half). Computes 16 atoms x 128 ch of
//    u (half=0) or v (half=1) as  D[c][atom] = sum_k W0h^T[c][k] * x[atom][k]
//    via mfma_f32_16x16x32_f16. W0-half gathered once into LDS frag layout.
//  blocks 256..263: w1f[(kk*8+nf)*64+lane][e] = f16(W1[kk*32+(lane>>4)*8+e]
//                                                    [nf*16+(lane&15)])
// ---------------------------------------------------------------------------
__global__ __launch_bounds__(256) void prep_kernel(
    const float* __restrict__ x, const float* __restrict__ W0,
    const float* __restrict__ b0, const float* __restrict__ W1,
    _Float16* __restrict__ u, _Float16* __restrict__ v,
    _Float16* __restrict__ w1f)
{
    int blk = blockIdx.x, tid = threadIdx.x;
    if (blk < 256) {
        __shared__ __align__(16) _Float16 w0h[32 * 64 * 8];  // 32 KB frag-major
        int b = blk >> 3, g = (blk >> 1) & 3, half = blk & 1;

        int lane = tid & 63, wave = tid >> 6;
        int llo = lane & 15, lhi = lane >> 4;

        // ---- x B-fragments from global (issued first, latency hidden)
        const float* xrow = x + ((size_t)b * NA + g * 16 + llo) * NF;
        f16x8 xf[4];
        #pragma unroll
        for (int kk = 0; kk < 4; ++kk) {
            f32x4 a0 = *(const f32x4*)(xrow + kk * 32 + lhi * 8);
            f32x4 a1 = *(const f32x4*)(xrow + kk * 32 + lhi * 8 + 4);
            #pragma unroll
            for (int e = 0; e < 4; ++e) {
                xf[kk][e]     = (_Float16)a0[e];
                xf[kk][e + 4] = (_Float16)a1[e];
            }
        }

        // ---- gather W0 half -> LDS A-frag layout (L2-hit scalar loads)
        #pragma unroll
        for (int p = 0; p < 8; ++p) {
            int sl   = p * 256 + tid;       // frag-slice 0..2047
            int frag = sl >> 6;             // kk*8 + nfc
            int ln   = sl & 63;
            int kk   = frag >> 3, nfc = frag & 7;
            int k0   = half * 128 + kk * 32 + (ln >> 4) * 8;
            int c    = nfc * 16 + (ln & 15);
            f16x8 o;
            #pragma unroll
            for (int e = 0; e < 8; ++e)
                o[e] = (_Float16)W0[(size_t)(k0 + e) * NC + c];
            *(f16x8*)(w0h + (size_t)sl * 8) = o;
        }
        __syncthreads();

        // ---- 8 MFMAs per wave: acc[t] = W0h^T frags (nfc=wave*2+t) x xf
        f32x4 acc[2];
        f32x4 z = {0.f, 0.f, 0.f, 0.f};
        acc[0] = z; acc[1] = z;
        #pragma unroll
        for (int kk = 0; kk < 4; ++kk) {
            #pragma unroll
            for (int t = 0; t < 2; ++t) {
                int nfc = wave * 2 + t;
                f16x8 aw = *(const f16x8*)(w0h +
                    (size_t)((kk * 8 + nfc) * 64 + lane) * 8);
                acc[t] = __builtin_amdgcn_mfma_f32_16x16x32_f16(
                    aw, xf[kk], acc[t], 0, 0, 0);
            }
        }

        // ---- store: D[c = nfc*16+lhi*4+q][atom = llo]
        _Float16* dst = half ? v : u;
        size_t arow = ((size_t)b * NA + g * 16 + llo) * NC;
        #pragma unroll
        for (int t = 0; t < 2; ++t) {
            int nfc = wave * 2 + t;
            int c0  = nfc * 16 + lhi * 4;
            f16x4 o;
            if (half) {
                f32x4 bb = *(const f32x4*)(b0 + c0);
                #pragma unroll
                for (int e = 0; e < 4; ++e)
                    o[e] = (_Float16)(acc[t][e] + bb[e]);
            } else {
                #pragma unroll
                for (int e = 0; e < 4; ++e)
                    o[e] = (_Float16)acc[t][e];
            }
            *(f16x4*)(dst + arow + c0) = o;
        }
    } else {
        int fl   = (blk - 256) * 256 + tid;   // 0..2047
        int lane = fl & 63;
        int frag = fl >> 6;                   // kk*8+nf
        int kk = frag >> 3, nf = frag & 7;
        int k0 = kk * 32 + (lane >> 4) * 8;
        int n  = nf * 16 + (lane & 15);
        f16x8 o;
        #pragma unroll
        for (int e = 0; e < 8; ++e)
            o[e] = (_Float16)W1[(size_t)(k0 + e) * NC + n];
        *(f16x8*)(w1f + (size_t)fl * 8) = o;
    }
}

// ---------------------------------------------------------------------------
// main: block = (batch b, unordered 8x8 atom tile pair (I<=J)), 256 thr.
// fp16 u/v tiles XOR-swizzled (chunk ^= row&7) -> uJ/vJ reads at the 4-way
// pigeonhole floor instead of 8-way; W1 frag-order in LDS; f16 MFMA.
// ---------------------------------------------------------------------------
__global__ __launch_bounds__(256, 3) void pair_mlp_kernel(
    const float* __restrict__ b1g, const _Float16* __restrict__ u,
    const _Float16* __restrict__ v, const _Float16* __restrict__ w1f,
    float* __restrict__ out)
{
    __shared__ __align__(16) _Float16 u_s[16 * 128];    // 4 KB
    __shared__ __align__(16) _Float16 v_s[16 * 128];    // 4 KB
    __shared__ __align__(16) _Float16 w_s[32 * 64 * 8]; // 32 KB frag-major

    int blk = blockIdx.x;
    int b = blk / 36;
    int t = blk % 36;
    int I = 0;
    while (t >= 8 - I) { t -= 8 - I; ++I; }
    int J = I + t;

    int tid = threadIdx.x;

    // ---- stage u/v tiles, swizzled: chunk = row*16 + (c ^ (row&7))
    {
        int row = tid >> 4;            // 0..15
        int c   = tid & 15;            // 16B chunk within 256B row
        int ga  = b * NA + ((row < 8) ? (I * 8 + row) : (J * 8 + (row & 7)));
        int sc  = row * 16 + (c ^ (row & 7));
        ((u32x4*)u_s)[sc] = ((const u32x4*)(u + (size_t)ga * NC))[c];
        ((u32x4*)v_s)[sc] = ((const u32x4*)(v + (size_t)ga * NC))[c];
    }
    // ---- stage W1 frags: 2048 contiguous 16B chunks
    #pragma unroll
    for (int p = 0; p < 8; ++p)
        ((u32x4*)w_s)[p * 256 + tid] = ((const u32x4*)w1f)[p * 256 + tid];
    __syncthreads();

    int wave = tid >> 6;
    int lane = tid & 63;
    int llo  = lane & 15;
    int lhi  = lane >> 4;
    int r    = wave * 16 + llo;
    int il   = r >> 3;            // 0..7
    int jl   = r & 7;             // 0..7

    f32x4 acc0[8], acc1[8];
    f32x4 z = {0.f, 0.f, 0.f, 0.f};
    #pragma unroll
    for (int nf = 0; nf < 8; ++nf) { acc0[nf] = z; acc1[nf] = z; }

    const f16x8* us = (const f16x8*)u_s;
    const f16x8* vs = (const f16x8*)v_s;
    const f16x8* wf = (const f16x8*)w_s;

    #pragma unroll
    for (int kk = 0; kk < 4; ++kk) {
        int kc  = kk * 4 + lhi;
        int scI = il * 16 + (kc ^ il);          // il&7 == il
        int scJ = (8 + jl) * 16 + (kc ^ jl);    // (8+jl)&7 == jl

        f16x8 uIv = us[scI];
        f16x8 vIv = vs[scI];
        f16x8 uJv = us[scJ];
        f16x8 vJv = vs[scJ];

        f16x8 s0 = uIv + vJv;
        f16x8 s1 = uJv + vIv;
        f16x8 h0, h1;
        #pragma unroll
        for (int e = 0; e < 8; ++e) {
            h0[e] = s0[e] < (_Float16)0 ? (_Float16)0 : s0[e];
            h1[e] = s1[e] < (_Float16)0 ? (_Float16)0 : s1[e];
        }

        #pragma unroll
        for (int nf = 0; nf < 8; ++nf) {
            f16x8 w = wf[(kk * 8 + nf) * 64 + lane];
            acc0[nf] = __builtin_amdgcn_mfma_f32_16x16x32_f16(w, h0, acc0[nf], 0, 0, 0);
            acc1[nf] = __builtin_amdgcn_mfma_f32_16x16x32_f16(w, h1, acc1[nf], 0, 0, 0);
        }
    }

    int Ig = I * 8 + il;
    int Jg = J * 8 + jl;
    float* p1 = out + ((size_t)b * 4096 + Ig * 64 + Jg) * 128 + lhi * 4;
    float* p2 = out + ((size_t)b * 4096 + Jg * 64 + Ig) * 128 + lhi * 4;
    bool mirror = (I != J);
    #pragma unroll
    for (int nf = 0; nf < 8; ++nf) {
        f32x4 bias = *(const f32x4*)(b1g + nf * 16 + lhi * 4);
        f32x4 val;
        #pragma unroll
        for (int e = 0; e < 4; ++e)
            val[e] = fmaxf(acc0[nf][e] + bias[e], 0.f) +
                     fmaxf(acc1[nf][e] + bias[e], 0.f);
        *(f32x4*)(p1 + nf * 16) = val;
        if (mirror)
            *(f32x4*)(p2 + nf * 16) = val;
    }
}

extern "C" void kernel_launch(void* const* d_in, const int* in_sizes, int n_in,
                              void* d_out, int out_size, void* d_ws, size_t ws_size,
                              hipStream_t stream)
{
    (void)in_sizes; (void)n_in; (void)out_size; (void)ws_size;
    const float* x  = (const float*)d_in[0];
    const float* W0 = (const float*)d_in[1];
    const float* b0 = (const float*)d_in[2];
    const float* W1 = (const float*)d_in[3];
    const float* b1 = (const float*)d_in[4];
    float* out = (float*)d_out;

    _Float16* u   = (_Float16*)d_ws;                       // 0.5 MB
    _Float16* v   = u + (size_t)NB * NA * NC;              // 0.5 MB
    _Float16* w1f = v + (size_t)NB * NA * NC;              // 32 KB

    prep_kernel<<<264, 256, 0, stream>>>(x, W0, b0, W1, u, v, w1f);
    pair_mlp_kernel<<<32 * 36, 256, 0, stream>>>(b1, u, v, w1f, out);
}